// Round 4
// baseline (411.268 us; speedup 1.0000x reference)
//
#include <hip/hip_runtime.h>

#define NSEQ 512
#define DD 128
#define NP (NSEQ * NSEQ)

typedef unsigned short u16;
typedef __attribute__((ext_vector_type(8))) unsigned short u16x8;
typedef __attribute__((ext_vector_type(4))) unsigned short u16x4;
typedef __attribute__((ext_vector_type(8))) short bf16x8;
typedef __attribute__((ext_vector_type(4))) float f32x4;

__device__ __forceinline__ u16 f2bf(float f) {
  unsigned int x = __float_as_uint(f);
  return (u16)((x + 0x7fffu + ((x >> 16) & 1u)) >> 16);  // RNE
}
__device__ __forceinline__ float bf2f(u16 u) {
  return __uint_as_float(((unsigned int)u) << 16);
}
__device__ __forceinline__ f32x4 mfma16(bf16x8 a, bf16x8 b, f32x4 c) {
  return __builtin_amdgcn_mfma_f32_16x16x32_bf16(a, b, c, 0, 0, 0);
}
__device__ __forceinline__ void gload16(const void* g, void* l) {
  __builtin_amdgcn_global_load_lds(
      (const __attribute__((address_space(1))) unsigned int*)g,
      (__attribute__((address_space(3))) unsigned int*)l, 16, 0, 0);
}
__device__ __forceinline__ float sigmoidf_(float v) { return 1.f / (1.f + __expf(-v)); }

// LayerNorm of 128 rows x 128 cols of fp32 -> bf16 LDS tile [128][136].
// 256 threads: 2 threads per row (halves), combined via shfl_xor(1).
// (still used by kC)
__device__ __forceinline__ void ln_stage(const float* __restrict__ xrow, u16* zl,
                                         const float* __restrict__ sc,
                                         const float* __restrict__ bi, int tid) {
  int r = tid >> 1, hf = tid & 1;
  const float* px = xrow + r * 128 + hf * 64;
  float s = 0.f, s2 = 0.f;
#pragma unroll
  for (int q = 0; q < 16; ++q) {
    float4 v = *(const float4*)(px + q * 4);
    s += v.x + v.y + v.z + v.w;
    s2 += v.x * v.x + v.y * v.y + v.z * v.z + v.w * v.w;
  }
  s += __shfl_xor(s, 1);
  s2 += __shfl_xor(s2, 1);
  float mu = s * (1.f / 128.f);
  float rs = rsqrtf(s2 * (1.f / 128.f) - mu * mu + 1e-5f);
#pragma unroll
  for (int q = 0; q < 16; ++q) {
    float4 v = *(const float4*)(px + q * 4);
    int c0 = hf * 64 + q * 4;
    u16x4 o;
    o[0] = f2bf((v.x - mu) * rs * sc[c0 + 0] + bi[c0 + 0]);
    o[1] = f2bf((v.y - mu) * rs * sc[c0 + 1] + bi[c0 + 1]);
    o[2] = f2bf((v.z - mu) * rs * sc[c0 + 2] + bi[c0 + 2]);
    o[3] = f2bf((v.w - mu) * rs * sc[c0 + 3] + bi[c0 + 3]);
    *(u16x4*)&zl[r * 136 + c0] = o;
  }
}

// ---------------- weight prep: fp32 [k][col] -> bf16 transposed [col][k] ----------------
__global__ void kW(const float* __restrict__ wa, const float* __restrict__ wga,
                   const float* __restrict__ wb, const float* __restrict__ wgb,
                   const float* __restrict__ wg, const float* __restrict__ wo,
                   u16* __restrict__ Wcat, u16* __restrict__ Wgt, u16* __restrict__ Wot) {
  int b = blockIdx.x, k = threadIdx.x;
  const float* src;
  u16* dst;
  int col;
  if (b < 512) {
    const float* m4[4] = {wa, wga, wb, wgb};
    src = m4[b >> 7];
    col = b & 127;
    dst = Wcat + (size_t)b * 128;
  } else if (b < 640) {
    src = wg;
    col = b - 512;
    dst = Wgt + (size_t)col * 128;
  } else {
    src = wo;
    col = b - 640;
    dst = Wot + (size_t)col * 128;
  }
  dst[k] = f2bf(src[k * 128 + col]);
}

// ---------------- kernel A: LN + 4 projections + gating -> n1_t, n2_t ([h][i][k] bf16) ----
// Single-pass LN (x held in regs), wave-private z slices (no block barrier), explicit
// double-buffered weight-fragment prefetch from global (L1/L2-resident).
__global__ __launch_bounds__(256, 4) void kA(const float* __restrict__ x,
                                             const float* __restrict__ zn_s,
                                             const float* __restrict__ zn_b,
                                             const float* __restrict__ b_a,
                                             const float* __restrict__ b_ga,
                                             const float* __restrict__ b_b,
                                             const float* __restrict__ b_gb,
                                             const u16* __restrict__ Wcat,
                                             u16* __restrict__ n1t, u16* __restrict__ n2t) {
  __shared__ __align__(16) u16 z[128 * 136];
  int tid = threadIdx.x;
  int pos0 = blockIdx.x * 128;
  int lane = tid & 63, w = tid >> 6;

  {  // ---- single-pass LN: 2 threads per row, x kept in registers ----
    int r = tid >> 1, hf = tid & 1;
    const float* px = x + (size_t)pos0 * 128 + r * 128 + hf * 64;
    float4 xv[16];
    float s = 0.f, s2 = 0.f;
#pragma unroll
    for (int q = 0; q < 16; ++q) {
      xv[q] = *(const float4*)(px + q * 4);
      s += xv[q].x + xv[q].y + xv[q].z + xv[q].w;
      s2 += xv[q].x * xv[q].x + xv[q].y * xv[q].y + xv[q].z * xv[q].z + xv[q].w * xv[q].w;
    }
    s += __shfl_xor(s, 1);
    s2 += __shfl_xor(s2, 1);
    float mu = s * (1.f / 128.f);
    float rs = rsqrtf(s2 * (1.f / 128.f) - mu * mu + 1e-5f);
#pragma unroll
    for (int q = 0; q < 16; ++q) {
      int c0 = hf * 64 + q * 4;
      u16x4 o;
      o[0] = f2bf((xv[q].x - mu) * rs * zn_s[c0 + 0] + zn_b[c0 + 0]);
      o[1] = f2bf((xv[q].y - mu) * rs * zn_s[c0 + 1] + zn_b[c0 + 1]);
      o[2] = f2bf((xv[q].z - mu) * rs * zn_s[c0 + 2] + zn_b[c0 + 2]);
      o[3] = f2bf((xv[q].w - mu) * rs * zn_s[c0 + 3] + zn_b[c0 + 3]);
      *(u16x4*)&z[r * 136 + c0] = o;
    }
  }
  // No __syncthreads: wave w wrote exactly rows [32w, 32w+32) and reads only those below;
  // same-wave LDS ordering is enforced by the compiler's lgkmcnt.

  bf16x8 af[2][4];
#pragma unroll
  for (int rf = 0; rf < 2; ++rf)
#pragma unroll
    for (int kf = 0; kf < 4; ++kf)
      af[rf][kf] = *(const bf16x8*)&z[(w * 32 + rf * 16 + (lane & 15)) * 136 + kf * 32 + (lane >> 4) * 8];

  int koff = (lane >> 4) * 8;
  int colL = lane & 15;

#pragma unroll 1
  for (int g = 0; g < 2; ++g) {
    const float* bxp = g ? b_b : b_a;
    const float* bgp = g ? b_gb : b_ga;
    u16* dst = g ? n2t : n1t;
    const u16* Wx = Wcat + (size_t)(g * 256) * 128;
    const u16* Wg_ = Wcat + (size_t)(g * 256 + 128) * 128;

    bf16x8 wxf[2][4], wgf[2][4];  // double-buffered weight fragments (static idx after unroll)
#pragma unroll
    for (int kf = 0; kf < 4; ++kf) {
      wxf[0][kf] = *(const bf16x8*)&Wx[(size_t)colL * 128 + kf * 32 + koff];
      wgf[0][kf] = *(const bf16x8*)&Wg_[(size_t)colL * 128 + kf * 32 + koff];
    }

#pragma unroll
    for (int cf = 0; cf < 8; ++cf) {
      int cb = cf & 1, nb = cb ^ 1;
      if (cf < 7) {
        int ncol = (cf + 1) * 16 + colL;
#pragma unroll
        for (int kf = 0; kf < 4; ++kf) {
          wxf[nb][kf] = *(const bf16x8*)&Wx[(size_t)ncol * 128 + kf * 32 + koff];
          wgf[nb][kf] = *(const bf16x8*)&Wg_[(size_t)ncol * 128 + kf * 32 + koff];
        }
      }
      f32x4 ax0 = {0.f, 0.f, 0.f, 0.f}, ax1 = ax0, ag0 = ax0, ag1 = ax0;
#pragma unroll
      for (int kf = 0; kf < 4; ++kf) {
        ax0 = mfma16(af[0][kf], wxf[cb][kf], ax0);
        ax1 = mfma16(af[1][kf], wxf[cb][kf], ax1);
        ag0 = mfma16(af[0][kf], wgf[cb][kf], ag0);
        ag1 = mfma16(af[1][kf], wgf[cb][kf], ag1);
      }
      int h = cf * 16 + colL;
      float bx_ = bxp[h], bg_ = bgp[h];
      size_t hb = (size_t)h * NP + pos0 + w * 32 + (lane >> 4) * 4;
      u16x4 o0, o1;
#pragma unroll
      for (int r = 0; r < 4; ++r) {
        o0[r] = f2bf((ax0[r] + bx_) * sigmoidf_(ag0[r] + bg_));
        o1[r] = f2bf((ax1[r] + bx_) * sigmoidf_(ag1[r] + bg_));
      }
      *(u16x4*)&dst[hb] = o0;
      *(u16x4*)&dst[hb + 16] = o1;
    }
  }
}

// ---------------- kernel B: per-h NT GEMM  P[h][i][j] = sum_k n1[h][i][k]*n2[h][j][k] -----
__global__ __launch_bounds__(256) void kB(const u16* __restrict__ n1t,
                                          const u16* __restrict__ n2t,
                                          u16* __restrict__ P) {
  __shared__ __align__(16) u16 At[2][128 * 64];
  __shared__ __align__(16) u16 Bt[2][128 * 64];
  int bid = blockIdx.x;
  int h = bid >> 4, t = bid & 15;
  int i0 = (t >> 2) * 128, j0 = (t & 3) * 128;
  const u16* Ab = n1t + (size_t)h * NP + (size_t)i0 * 512;
  const u16* Bb = n2t + (size_t)h * NP + (size_t)j0 * 512;
  int tid = threadIdx.x, lane = tid & 63, w = tid >> 6;

  f32x4 acc[4][4];
#pragma unroll
  for (int a_ = 0; a_ < 4; ++a_)
#pragma unroll
    for (int b_ = 0; b_ < 4; ++b_) acc[a_][b_] = f32x4{0.f, 0.f, 0.f, 0.f};

  auto STAGE = [&](int buf, int kt) {
#pragma unroll
    for (int q = 0; q < 4; ++q) {
      int c = q * 256 + tid;
      int row = c >> 3, ch = c & 7;
      int chG = ch ^ (row & 7);
      gload16(Ab + (size_t)row * 512 + kt * 64 + chG * 8, &At[buf][c * 8]);
    }
#pragma unroll
    for (int q = 0; q < 4; ++q) {
      int c = q * 256 + tid;
      int row = c >> 3, ch = c & 7;
      int chG = ch ^ (row & 7);
      gload16(Bb + (size_t)row * 512 + kt * 64 + chG * 8, &Bt[buf][c * 8]);
    }
  };

  STAGE(0, 0);
  int cur = 0;
  int r0 = (w >> 1) * 64, c0 = (w & 1) * 64;
#pragma unroll 1
  for (int kt = 0; kt < 8; ++kt) {
    if (kt < 7) {
      STAGE(cur ^ 1, kt + 1);
      __builtin_amdgcn_sched_barrier(0);
      asm volatile("s_waitcnt vmcnt(8)" ::: "memory");  // only current buf's 8 loads drained
    } else {
      asm volatile("s_waitcnt vmcnt(0)" ::: "memory");
    }
    __builtin_amdgcn_sched_barrier(0);
    __builtin_amdgcn_s_barrier();
    __builtin_amdgcn_sched_barrier(0);
#pragma unroll
    for (int kf = 0; kf < 2; ++kf) {
      bf16x8 a[4], b[4];
#pragma unroll
      for (int rf = 0; rf < 4; ++rf) {
        int row = r0 + rf * 16 + (lane & 15);
        a[rf] = *(const bf16x8*)&At[cur][row * 64 + (((kf * 4 + (lane >> 4)) ^ (row & 7)) * 8)];
      }
#pragma unroll
      for (int cf = 0; cf < 4; ++cf) {
        int row = c0 + cf * 16 + (lane & 15);
        b[cf] = *(const bf16x8*)&Bt[cur][row * 64 + (((kf * 4 + (lane >> 4)) ^ (row & 7)) * 8)];
      }
#pragma unroll
      for (int rf = 0; rf < 4; ++rf)
#pragma unroll
        for (int cf = 0; cf < 4; ++cf) acc[rf][cf] = mfma16(a[rf], b[cf], acc[rf][cf]);
    }
    __builtin_amdgcn_sched_barrier(0);
    __builtin_amdgcn_s_barrier();
    __builtin_amdgcn_sched_barrier(0);
    cur ^= 1;
  }

  size_t Pb = (size_t)h * NP;
#pragma unroll
  for (int rf = 0; rf < 4; ++rf)
#pragma unroll
    for (int cf = 0; cf < 4; ++cf) {
      int ii = i0 + (w >> 1) * 64 + rf * 16 + (lane >> 4) * 4;
      int jj = j0 + (w & 1) * 64 + cf * 16 + (lane & 15);
#pragma unroll
      for (int r = 0; r < 4; ++r) P[Pb + (size_t)(ii + r) * 512 + jj] = f2bf(acc[rf][cf][r]);
    }
}

// ---------------- kernel C: LN over h, @w_o + b_o, * sigmoid(z@w_g + b_g) -----------------
__global__ __launch_bounds__(256) void kC(const float* __restrict__ x, const u16* __restrict__ P,
                                          const float* __restrict__ zn_s,
                                          const float* __restrict__ zn_b,
                                          const float* __restrict__ ln_s,
                                          const float* __restrict__ ln_b,
                                          const u16* __restrict__ Wot, const u16* __restrict__ Wgt,
                                          const float* __restrict__ b_o,
                                          const float* __restrict__ b_g,
                                          float* __restrict__ out) {
  __shared__ __align__(16) u16 Pt[128 * 136];   // [j][h], LN'd in place
  __shared__ __align__(16) u16 Zx[128 * 136];   // LN(x) rows [j][c]
  __shared__ __align__(16) u16 WoL[128 * 136];
  __shared__ __align__(16) u16 WgL[128 * 136];
  int tid = threadIdx.x;
  int i = blockIdx.x >> 2, jb = blockIdx.x & 3;
  size_t pos0 = (size_t)i * 512 + jb * 128;

  ln_stage(x + pos0 * 128, Zx, zn_s, zn_b, tid);
  for (int c = tid; c < 2048; c += 256) {  // full 128x128 tiles: 2048 chunks of 8 u16
    *(u16x8*)&WoL[(c >> 4) * 136 + (c & 15) * 8] = *(const u16x8*)&Wot[c * 8];
    *(u16x8*)&WgL[(c >> 4) * 136 + (c & 15) * 8] = *(const u16x8*)&Wgt[c * 8];
  }
  {  // transpose-stage P[h][i][j0:j0+128] -> Pt[j][h]
    int hh = tid >> 1, part = tid & 1;
    const u16* src = P + (size_t)hh * NP + pos0 + part * 64;
#pragma unroll
    for (int q = 0; q < 8; ++q) {
      u16x8 v = *(const u16x8*)(src + q * 8);
#pragma unroll
      for (int e = 0; e < 8; ++e) Pt[(part * 64 + q * 8 + e) * 136 + hh] = v[e];
    }
  }
  __syncthreads();

  if (tid < 128) {  // LN stats over h, normalize in place
    float s = 0.f, s2 = 0.f;
#pragma unroll
    for (int q = 0; q < 16; ++q) {
      u16x8 v = *(const u16x8*)&Pt[tid * 136 + q * 8];
#pragma unroll
      for (int e = 0; e < 8; ++e) {
        float f = bf2f(v[e]);
        s += f;
        s2 += f * f;
      }
    }
    float mu = s * (1.f / 128.f);
    float rs = rsqrtf(s2 * (1.f / 128.f) - mu * mu + 1e-5f);
#pragma unroll
    for (int q = 0; q < 16; ++q) {
      u16x8 v = *(const u16x8*)&Pt[tid * 136 + q * 8];
      u16x8 o;
#pragma unroll
      for (int e = 0; e < 8; ++e) {
        int hh = q * 8 + e;
        o[e] = f2bf((bf2f(v[e]) - mu) * rs * ln_s[hh] + ln_b[hh]);
      }
      *(u16x8*)&Pt[tid * 136 + q * 8] = o;
    }
  }
  __syncthreads();

  int lane = tid & 63, w = tid >> 6;
  bf16x8 ap[2][4], az[2][4];
#pragma unroll
  for (int rf = 0; rf < 2; ++rf)
#pragma unroll
    for (int kf = 0; kf < 4; ++kf) {
      int row = (w * 32 + rf * 16 + (lane & 15)) * 136 + kf * 32 + (lane >> 4) * 8;
      ap[rf][kf] = *(const bf16x8*)&Pt[row];
      az[rf][kf] = *(const bf16x8*)&Zx[row];
    }

#pragma unroll 1
  for (int sub = 0; sub < 4; ++sub) {
    f32x4 au[2][2], agg[2][2];
#pragma unroll
    for (int rf = 0; rf < 2; ++rf)
#pragma unroll
      for (int cf = 0; cf < 2; ++cf) {
        au[rf][cf] = f32x4{0.f, 0.f, 0.f, 0.f};
        agg[rf][cf] = f32x4{0.f, 0.f, 0.f, 0.f};
      }
#pragma unroll
    for (int kf = 0; kf < 4; ++kf)
#pragma unroll
      for (int cf = 0; cf < 2; ++cf) {
        int wrow = (sub * 32 + cf * 16 + (lane & 15)) * 136 + kf * 32 + (lane >> 4) * 8;
        bf16x8 bo_f = *(const bf16x8*)&WoL[wrow];
        bf16x8 bg_f = *(const bf16x8*)&WgL[wrow];
#pragma unroll
        for (int rf = 0; rf < 2; ++rf) {
          au[rf][cf] = mfma16(ap[rf][kf], bo_f, au[rf][cf]);
          agg[rf][cf] = mfma16(az[rf][kf], bg_f, agg[rf][cf]);
        }
      }
#pragma unroll
    for (int rf = 0; rf < 2; ++rf)
#pragma unroll
      for (int cf = 0; cf < 2; ++cf) {
        int d = sub * 32 + cf * 16 + (lane & 15);
        float bo_ = b_o[d], bg_ = b_g[d];
        int jl = w * 32 + rf * 16 + (lane >> 4) * 4;
#pragma unroll
        for (int r = 0; r < 4; ++r) {
          float uv = au[rf][cf][r] + bo_;
          out[(pos0 + jl + r) * 128 + d] = uv * sigmoidf_(agg[rf][cf][r] + bg_);
        }
      }
  }
}

extern "C" void kernel_launch(void* const* d_in, const int* in_sizes, int n_in,
                              void* d_out, int out_size, void* d_ws, size_t ws_size,
                              hipStream_t stream) {
  const float* x = (const float*)d_in[0];
  const float* zn_s = (const float*)d_in[1];
  const float* zn_b = (const float*)d_in[2];
  const float* ln_s = (const float*)d_in[3];
  const float* ln_b = (const float*)d_in[4];
  const float* w_a = (const float*)d_in[5];
  const float* b_a = (const float*)d_in[6];
  const float* w_ga = (const float*)d_in[7];
  const float* b_ga = (const float*)d_in[8];
  const float* w_b = (const float*)d_in[9];
  const float* b_b = (const float*)d_in[10];
  const float* w_gb = (const float*)d_in[11];
  const float* b_gb = (const float*)d_in[12];
  const float* w_o = (const float*)d_in[13];
  const float* b_o = (const float*)d_in[14];
  const float* w_g = (const float*)d_in[15];
  const float* b_g = (const float*)d_in[16];

  char* ws = (char*)d_ws;
  u16* n1t = (u16*)ws;                                  // [128][512][512] bf16, 64 MB
  u16* n2t = (u16*)(ws + 67108864);                     // 64 MB
  u16* P = (u16*)(ws + 134217728);                      // [128][512][512] bf16, 64 MB
  u16* Wcat = (u16*)(ws + 201326592);                   // [512 cols][128 k] bf16
  u16* Wgt = (u16*)(ws + 201326592 + 131072);           // [128][128]
  u16* Wot = (u16*)(ws + 201326592 + 131072 + 32768);   // [128][128]

  kW<<<768, 128, 0, stream>>>(w_a, w_ga, w_b, w_gb, w_g, w_o, Wcat, Wgt, Wot);
  kA<<<2048, 256, 0, stream>>>(x, zn_s, zn_b, b_a, b_ga, b_b, b_gb, Wcat, n1t, n2t);
  kB<<<2048, 256, 0, stream>>>(n1t, n2t, P);
  kC<<<2048, 256, 0, stream>>>(x, P, zn_s, zn_b, ln_s, ln_b, Wot, Wgt, b_o, b_g, (float*)d_out);
}

// Round 6
// 345.700 us; speedup vs baseline: 1.1897x; 1.1897x over previous
//
#include <hip/hip_runtime.h>

#define NSEQ 512
#define DD 128
#define NP (NSEQ * NSEQ)

typedef unsigned short u16;
typedef __attribute__((ext_vector_type(8))) unsigned short u16x8;
typedef __attribute__((ext_vector_type(4))) unsigned short u16x4;
typedef __attribute__((ext_vector_type(8))) short bf16x8;
typedef __attribute__((ext_vector_type(4))) float f32x4;

__device__ __forceinline__ u16 f2bf(float f) {
  unsigned int x = __float_as_uint(f);
  return (u16)((x + 0x7fffu + ((x >> 16) & 1u)) >> 16);  // RNE
}
__device__ __forceinline__ float bf2f(u16 u) {
  return __uint_as_float(((unsigned int)u) << 16);
}
__device__ __forceinline__ f32x4 mfma16(bf16x8 a, bf16x8 b, f32x4 c) {
  return __builtin_amdgcn_mfma_f32_16x16x32_bf16(a, b, c, 0, 0, 0);
}
__device__ __forceinline__ void gload16(const void* g, void* l) {
  __builtin_amdgcn_global_load_lds(
      (const __attribute__((address_space(1))) unsigned int*)g,
      (__attribute__((address_space(3))) unsigned int*)l, 16, 0, 0);
}
__device__ __forceinline__ float sigmoidf_(float v) { return 1.f / (1.f + __expf(-v)); }

// LayerNorm of 128 rows x 128 cols of fp32 -> bf16 LDS tile [128][136]. (used by kC)
__device__ __forceinline__ void ln_stage(const float* __restrict__ xrow, u16* zl,
                                         const float* __restrict__ sc,
                                         const float* __restrict__ bi, int tid) {
  int r = tid >> 1, hf = tid & 1;
  const float* px = xrow + r * 128 + hf * 64;
  float s = 0.f, s2 = 0.f;
#pragma unroll
  for (int q = 0; q < 16; ++q) {
    float4 v = *(const float4*)(px + q * 4);
    s += v.x + v.y + v.z + v.w;
    s2 += v.x * v.x + v.y * v.y + v.z * v.z + v.w * v.w;
  }
  s += __shfl_xor(s, 1);
  s2 += __shfl_xor(s2, 1);
  float mu = s * (1.f / 128.f);
  float rs = rsqrtf(s2 * (1.f / 128.f) - mu * mu + 1e-5f);
#pragma unroll
  for (int q = 0; q < 16; ++q) {
    float4 v = *(const float4*)(px + q * 4);
    int c0 = hf * 64 + q * 4;
    u16x4 o;
    o[0] = f2bf((v.x - mu) * rs * sc[c0 + 0] + bi[c0 + 0]);
    o[1] = f2bf((v.y - mu) * rs * sc[c0 + 1] + bi[c0 + 1]);
    o[2] = f2bf((v.z - mu) * rs * sc[c0 + 2] + bi[c0 + 2]);
    o[3] = f2bf((v.w - mu) * rs * sc[c0 + 3] + bi[c0 + 3]);
    *(u16x4*)&zl[r * 136 + c0] = o;
  }
}

// ---------------- weight prep ----------------
// For kA: pack {wa,wga,wb,wgb} in MFMA B-fragment order, kf in 0..3 (K=128):
//   Wp[m*16384 + (cf*4+kf)*512 + lane*8 + e] = bf16( w_m[kf*32 + (lane>>4)*8 + e][cf*16 + (lane&15)] )
// One matrix = 32 fragments x 512 = 16384 u16. Wave fragment load = base + lane*16B, coalesced.
// For kC: Wgt/Wot stay [col][k] transposed.
__global__ void kW(const float* __restrict__ wa, const float* __restrict__ wga,
                   const float* __restrict__ wb, const float* __restrict__ wgb,
                   const float* __restrict__ wg, const float* __restrict__ wo,
                   u16* __restrict__ Wp, u16* __restrict__ Wgt, u16* __restrict__ Wot) {
  int b = blockIdx.x, t = threadIdx.x;
  if (b < 128) {
    int m = b >> 5, cf = (b >> 2) & 7, kf = b & 3;
    const float* m4[4] = {wa, wga, wb, wgb};
    const float* src = m4[m];
    int lane = t >> 1, e0 = (t & 1) * 4;
    u16* dst = Wp + m * 16384 + (cf * 4 + kf) * 512 + lane * 8 + e0;
    int col = cf * 16 + (lane & 15);
    int row0 = kf * 32 + (lane >> 4) * 8 + e0;
#pragma unroll
    for (int e = 0; e < 4; ++e) dst[e] = f2bf(src[(row0 + e) * 128 + col]);
  } else if (b < 256) {
    int col = b - 128;
    Wgt[(size_t)col * 128 + t] = f2bf(wg[t * 128 + col]);
  } else {
    int col = b - 256;
    Wot[(size_t)col * 128 + t] = f2bf(wo[t * 128 + col]);
  }
}

// ---------------- kernel A: LN + 4 projections + gating -> n1_t, n2_t ([h][i][k] bf16) ----
// Single-pass LN (x in regs), packed coalesced weight fragments, 2-deep prefetch.
// amdgpu_waves_per_eu(4,4): LDS caps us at 4 blocks/CU anyway -> unlock 128 VGPRs.
__global__ void __launch_bounds__(256)
    __attribute__((amdgpu_waves_per_eu(4, 4)))
    kA(const float* __restrict__ x, const float* __restrict__ zn_s,
       const float* __restrict__ zn_b, const float* __restrict__ b_a,
       const float* __restrict__ b_ga, const float* __restrict__ b_b,
       const float* __restrict__ b_gb, const u16* __restrict__ Wp,
       u16* __restrict__ n1t, u16* __restrict__ n2t) {
  __shared__ __align__(16) u16 z[128 * 136];
  int tid = threadIdx.x;
  int pos0 = blockIdx.x * 128;
  int lane = tid & 63, w = tid >> 6;

  {  // ---- single-pass LN: 2 threads per row, x held in registers ----
    int r = tid >> 1, hf = tid & 1;
    const float* px = x + (size_t)pos0 * 128 + r * 128 + hf * 64;
    float4 xv[16];
    float s = 0.f, s2 = 0.f;
#pragma unroll
    for (int q = 0; q < 16; ++q) {
      xv[q] = *(const float4*)(px + q * 4);
      s += xv[q].x + xv[q].y + xv[q].z + xv[q].w;
      s2 += xv[q].x * xv[q].x + xv[q].y * xv[q].y + xv[q].z * xv[q].z + xv[q].w * xv[q].w;
    }
    s += __shfl_xor(s, 1);
    s2 += __shfl_xor(s2, 1);
    float mu = s * (1.f / 128.f);
    float rs = rsqrtf(s2 * (1.f / 128.f) - mu * mu + 1e-5f);
#pragma unroll
    for (int q = 0; q < 16; ++q) {
      int c0 = hf * 64 + q * 4;
      u16x4 o;
      o[0] = f2bf((xv[q].x - mu) * rs * zn_s[c0 + 0] + zn_b[c0 + 0]);
      o[1] = f2bf((xv[q].y - mu) * rs * zn_s[c0 + 1] + zn_b[c0 + 1]);
      o[2] = f2bf((xv[q].z - mu) * rs * zn_s[c0 + 2] + zn_b[c0 + 2]);
      o[3] = f2bf((xv[q].w - mu) * rs * zn_s[c0 + 3] + zn_b[c0 + 3]);
      *(u16x4*)&z[r * 136 + c0] = o;
    }
  }
  __syncthreads();  // keeps waves in lockstep (write coalescing) + z visibility

  bf16x8 af[2][4];
#pragma unroll
  for (int rf = 0; rf < 2; ++rf)
#pragma unroll
    for (int kf = 0; kf < 4; ++kf)
      af[rf][kf] = *(const bf16x8*)&z[(w * 32 + rf * 16 + (lane & 15)) * 136 + kf * 32 + (lane >> 4) * 8];

  int colL = lane & 15;

#pragma unroll 1
  for (int g = 0; g < 2; ++g) {
    const float* bxp = g ? b_b : b_a;
    const float* bgp = g ? b_gb : b_ga;
    u16* dst = g ? n2t : n1t;
    const u16* WxP = Wp + (g * 2) * 16384 + lane * 8;        // x-proj matrix, fragment order
    const u16* WgP = Wp + (g * 2 + 1) * 16384 + lane * 8;    // gate matrix

    bf16x8 wxf[2][4], wgf[2][4];  // 2-deep double buffer
#pragma unroll
    for (int kf = 0; kf < 4; ++kf) {
      wxf[0][kf] = *(const bf16x8*)&WxP[kf * 512];
      wgf[0][kf] = *(const bf16x8*)&WgP[kf * 512];
    }

#pragma unroll
    for (int cf = 0; cf < 8; ++cf) {
      int cb = cf & 1, nb = cb ^ 1;
      if (cf < 7) {
#pragma unroll
        for (int kf = 0; kf < 4; ++kf) {
          wxf[nb][kf] = *(const bf16x8*)&WxP[((cf + 1) * 4 + kf) * 512];
          wgf[nb][kf] = *(const bf16x8*)&WgP[((cf + 1) * 4 + kf) * 512];
        }
      }
      f32x4 ax0 = {0.f, 0.f, 0.f, 0.f}, ax1 = ax0, ag0 = ax0, ag1 = ax0;
#pragma unroll
      for (int kf = 0; kf < 4; ++kf) {
        ax0 = mfma16(af[0][kf], wxf[cb][kf], ax0);
        ax1 = mfma16(af[1][kf], wxf[cb][kf], ax1);
        ag0 = mfma16(af[0][kf], wgf[cb][kf], ag0);
        ag1 = mfma16(af[1][kf], wgf[cb][kf], ag1);
      }
      int h = cf * 16 + colL;
      float bx_ = bxp[h], bg_ = bgp[h];
      size_t hb = (size_t)h * NP + pos0 + w * 32 + (lane >> 4) * 4;
      u16x4 o0, o1;
#pragma unroll
      for (int r = 0; r < 4; ++r) {
        o0[r] = f2bf((ax0[r] + bx_) * sigmoidf_(ag0[r] + bg_));
        o1[r] = f2bf((ax1[r] + bx_) * sigmoidf_(ag1[r] + bg_));
      }
      *(u16x4*)&dst[hb] = o0;
      *(u16x4*)&dst[hb + 16] = o1;
    }
  }
}

// ---------------- kernel B: per-h NT GEMM  P[h][i][j] = sum_k n1[h][i][k]*n2[h][j][k] -----
__global__ __launch_bounds__(256) void kB(const u16* __restrict__ n1t,
                                          const u16* __restrict__ n2t,
                                          u16* __restrict__ P) {
  __shared__ __align__(16) u16 At[2][128 * 64];
  __shared__ __align__(16) u16 Bt[2][128 * 64];
  int bid = blockIdx.x;
  int h = bid >> 4, t = bid & 15;
  int i0 = (t >> 2) * 128, j0 = (t & 3) * 128;
  const u16* Ab = n1t + (size_t)h * NP + (size_t)i0 * 512;
  const u16* Bb = n2t + (size_t)h * NP + (size_t)j0 * 512;
  int tid = threadIdx.x, lane = tid & 63, w = tid >> 6;

  f32x4 acc[4][4];
#pragma unroll
  for (int a_ = 0; a_ < 4; ++a_)
#pragma unroll
    for (int b_ = 0; b_ < 4; ++b_) acc[a_][b_] = f32x4{0.f, 0.f, 0.f, 0.f};

  auto STAGE = [&](int buf, int kt) {
#pragma unroll
    for (int q = 0; q < 4; ++q) {
      int c = q * 256 + tid;
      int row = c >> 3, ch = c & 7;
      int chG = ch ^ (row & 7);
      gload16(Ab + (size_t)row * 512 + kt * 64 + chG * 8, &At[buf][c * 8]);
    }
#pragma unroll
    for (int q = 0; q < 4; ++q) {
      int c = q * 256 + tid;
      int row = c >> 3, ch = c & 7;
      int chG = ch ^ (row & 7);
      gload16(Bb + (size_t)row * 512 + kt * 64 + chG * 8, &Bt[buf][c * 8]);
    }
  };

  STAGE(0, 0);
  int cur = 0;
  int r0 = (w >> 1) * 64, c0 = (w & 1) * 64;
#pragma unroll 1
  for (int kt = 0; kt < 8; ++kt) {
    if (kt < 7) {
      STAGE(cur ^ 1, kt + 1);
      __builtin_amdgcn_sched_barrier(0);
      asm volatile("s_waitcnt vmcnt(8)" ::: "memory");  // only current buf's 8 loads drained
    } else {
      asm volatile("s_waitcnt vmcnt(0)" ::: "memory");
    }
    __builtin_amdgcn_sched_barrier(0);
    __builtin_amdgcn_s_barrier();
    __builtin_amdgcn_sched_barrier(0);
#pragma unroll
    for (int kf = 0; kf < 2; ++kf) {
      bf16x8 a[4], b[4];
#pragma unroll
      for (int rf = 0; rf < 4; ++rf) {
        int row = r0 + rf * 16 + (lane & 15);
        a[rf] = *(const bf16x8*)&At[cur][row * 64 + (((kf * 4 + (lane >> 4)) ^ (row & 7)) * 8)];
      }
#pragma unroll
      for (int cf = 0; cf < 4; ++cf) {
        int row = c0 + cf * 16 + (lane & 15);
        b[cf] = *(const bf16x8*)&Bt[cur][row * 64 + (((kf * 4 + (lane >> 4)) ^ (row & 7)) * 8)];
      }
#pragma unroll
      for (int rf = 0; rf < 4; ++rf)
#pragma unroll
        for (int cf = 0; cf < 4; ++cf) acc[rf][cf] = mfma16(a[rf], b[cf], acc[rf][cf]);
    }
    __builtin_amdgcn_sched_barrier(0);
    __builtin_amdgcn_s_barrier();
    __builtin_amdgcn_sched_barrier(0);
    cur ^= 1;
  }

  size_t Pb = (size_t)h * NP;
#pragma unroll
  for (int rf = 0; rf < 4; ++rf)
#pragma unroll
    for (int cf = 0; cf < 4; ++cf) {
      int ii = i0 + (w >> 1) * 64 + rf * 16 + (lane >> 4) * 4;
      int jj = j0 + (w & 1) * 64 + cf * 16 + (lane & 15);
#pragma unroll
      for (int r = 0; r < 4; ++r) P[Pb + (size_t)(ii + r) * 512 + jj] = f2bf(acc[rf][cf][r]);
    }
}

// ---------------- kernel C: LN over h, @w_o + b_o, * sigmoid(z@w_g + b_g) -----------------
__global__ __launch_bounds__(256) void kC(const float* __restrict__ x, const u16* __restrict__ P,
                                          const float* __restrict__ zn_s,
                                          const float* __restrict__ zn_b,
                                          const float* __restrict__ ln_s,
                                          const float* __restrict__ ln_b,
                                          const u16* __restrict__ Wot, const u16* __restrict__ Wgt,
                                          const float* __restrict__ b_o,
                                          const float* __restrict__ b_g,
                                          float* __restrict__ out) {
  __shared__ __align__(16) u16 Pt[128 * 136];   // [j][h], LN'd in place
  __shared__ __align__(16) u16 Zx[128 * 136];   // LN(x) rows [j][c]
  __shared__ __align__(16) u16 WoL[128 * 136];
  __shared__ __align__(16) u16 WgL[128 * 136];
  int tid = threadIdx.x;
  int i = blockIdx.x >> 2, jb = blockIdx.x & 3;
  size_t pos0 = (size_t)i * 512 + jb * 128;

  ln_stage(x + pos0 * 128, Zx, zn_s, zn_b, tid);
  for (int c = tid; c < 2048; c += 256) {  // full 128x128 tiles: 2048 chunks of 8 u16
    *(u16x8*)&WoL[(c >> 4) * 136 + (c & 15) * 8] = *(const u16x8*)&Wot[c * 8];
    *(u16x8*)&WgL[(c >> 4) * 136 + (c & 15) * 8] = *(const u16x8*)&Wgt[c * 8];
  }
  {  // transpose-stage P[h][i][j0:j0+128] -> Pt[j][h]
    int hh = tid >> 1, part = tid & 1;
    const u16* src = P + (size_t)hh * NP + pos0 + part * 64;
#pragma unroll
    for (int q = 0; q < 8; ++q) {
      u16x8 v = *(const u16x8*)(src + q * 8);
#pragma unroll
      for (int e = 0; e < 8; ++e) Pt[(part * 64 + q * 8 + e) * 136 + hh] = v[e];
    }
  }
  __syncthreads();

  if (tid < 128) {  // LN stats over h, normalize in place
    float s = 0.f, s2 = 0.f;
#pragma unroll
    for (int q = 0; q < 16; ++q) {
      u16x8 v = *(const u16x8*)&Pt[tid * 136 + q * 8];
#pragma unroll
      for (int e = 0; e < 8; ++e) {
        float f = bf2f(v[e]);
        s += f;
        s2 += f * f;
      }
    }
    float mu = s * (1.f / 128.f);
    float rs = rsqrtf(s2 * (1.f / 128.f) - mu * mu + 1e-5f);
#pragma unroll
    for (int q = 0; q < 16; ++q) {
      u16x8 v = *(const u16x8*)&Pt[tid * 136 + q * 8];
      u16x8 o;
#pragma unroll
      for (int e = 0; e < 8; ++e) {
        int hh = q * 8 + e;
        o[e] = f2bf((bf2f(v[e]) - mu) * rs * ln_s[hh] + ln_b[hh]);
      }
      *(u16x8*)&Pt[tid * 136 + q * 8] = o;
    }
  }
  __syncthreads();

  int lane = tid & 63, w = tid >> 6;
  bf16x8 ap[2][4], az[2][4];
#pragma unroll
  for (int rf = 0; rf < 2; ++rf)
#pragma unroll
    for (int kf = 0; kf < 4; ++kf) {
      int row = (w * 32 + rf * 16 + (lane & 15)) * 136 + kf * 32 + (lane >> 4) * 8;
      ap[rf][kf] = *(const bf16x8*)&Pt[row];
      az[rf][kf] = *(const bf16x8*)&Zx[row];
    }

#pragma unroll 1
  for (int sub = 0; sub < 4; ++sub) {
    f32x4 au[2][2], agg[2][2];
#pragma unroll
    for (int rf = 0; rf < 2; ++rf)
#pragma unroll
      for (int cf = 0; cf < 2; ++cf) {
        au[rf][cf] = f32x4{0.f, 0.f, 0.f, 0.f};
        agg[rf][cf] = f32x4{0.f, 0.f, 0.f, 0.f};
      }
#pragma unroll
    for (int kf = 0; kf < 4; ++kf)
#pragma unroll
      for (int cf = 0; cf < 2; ++cf) {
        int wrow = (sub * 32 + cf * 16 + (lane & 15)) * 136 + kf * 32 + (lane >> 4) * 8;
        bf16x8 bo_f = *(const bf16x8*)&WoL[wrow];
        bf16x8 bg_f = *(const bf16x8*)&WgL[wrow];
#pragma unroll
        for (int rf = 0; rf < 2; ++rf) {
          au[rf][cf] = mfma16(ap[rf][kf], bo_f, au[rf][cf]);
          agg[rf][cf] = mfma16(az[rf][kf], bg_f, agg[rf][cf]);
        }
      }
#pragma unroll
    for (int rf = 0; rf < 2; ++rf)
#pragma unroll
      for (int cf = 0; cf < 2; ++cf) {
        int d = sub * 32 + cf * 16 + (lane & 15);
        float bo_ = b_o[d], bg_ = b_g[d];
        int jl = w * 32 + rf * 16 + (lane >> 4) * 4;
#pragma unroll
        for (int r = 0; r < 4; ++r) {
          float uv = au[rf][cf][r] + bo_;
          out[(pos0 + jl + r) * 128 + d] = uv * sigmoidf_(agg[rf][cf][r] + bg_);
        }
      }
  }
}

extern "C" void kernel_launch(void* const* d_in, const int* in_sizes, int n_in,
                              void* d_out, int out_size, void* d_ws, size_t ws_size,
                              hipStream_t stream) {
  const float* x = (const float*)d_in[0];
  const float* zn_s = (const float*)d_in[1];
  const float* zn_b = (const float*)d_in[2];
  const float* ln_s = (const float*)d_in[3];
  const float* ln_b = (const float*)d_in[4];
  const float* w_a = (const float*)d_in[5];
  const float* b_a = (const float*)d_in[6];
  const float* w_ga = (const float*)d_in[7];
  const float* b_ga = (const float*)d_in[8];
  const float* w_b = (const float*)d_in[9];
  const float* b_b = (const float*)d_in[10];
  const float* w_gb = (const float*)d_in[11];
  const float* b_gb = (const float*)d_in[12];
  const float* w_o = (const float*)d_in[13];
  const float* b_o = (const float*)d_in[14];
  const float* w_g = (const float*)d_in[15];
  const float* b_g = (const float*)d_in[16];

  char* ws = (char*)d_ws;
  u16* n1t = (u16*)ws;                                  // [128][512][512] bf16, 64 MB
  u16* n2t = (u16*)(ws + 67108864);                     // 64 MB
  u16* P = (u16*)(ws + 134217728);                      // [128][512][512] bf16, 64 MB
  u16* Wp = (u16*)(ws + 201326592);                     // packed 4x[128x128] bf16, 128 KB
  u16* Wgt = (u16*)(ws + 201326592 + 131072);           // [128][128]
  u16* Wot = (u16*)(ws + 201326592 + 131072 + 32768);   // [128][128]

  kW<<<384, 128, 0, stream>>>(w_a, w_ga, w_b, w_gb, w_g, w_o, Wp, Wgt, Wot);
  kA<<<2048, 256, 0, stream>>>(x, zn_s, zn_b, b_a, b_ga, b_b, b_gb, Wp, n1t, n2t);
  kB<<<2048, 256, 0, stream>>>(n1t, n2t, P);
  kC<<<2048, 256, 0, stream>>>(x, P, zn_s, zn_b, ln_s, ln_b, Wot, Wgt, b_o, b_g, (float*)d_out);
}

// Round 7
// 306.821 us; speedup vs baseline: 1.3404x; 1.1267x over previous
//
#include <hip/hip_runtime.h>

#define NSEQ 512
#define DD 128
#define NP (NSEQ * NSEQ)

typedef unsigned short u16;
typedef __attribute__((ext_vector_type(8))) unsigned short u16x8;
typedef __attribute__((ext_vector_type(4))) unsigned short u16x4;
typedef __attribute__((ext_vector_type(8))) short bf16x8;
typedef __attribute__((ext_vector_type(4))) float f32x4;

__device__ __forceinline__ u16 f2bf(float f) {
  unsigned int x = __float_as_uint(f);
  return (u16)((x + 0x7fffu + ((x >> 16) & 1u)) >> 16);  // RNE
}
__device__ __forceinline__ float bf2f(u16 u) {
  return __uint_as_float(((unsigned int)u) << 16);
}
__device__ __forceinline__ f32x4 mfma16(bf16x8 a, bf16x8 b, f32x4 c) {
  return __builtin_amdgcn_mfma_f32_16x16x32_bf16(a, b, c, 0, 0, 0);
}
__device__ __forceinline__ void gload16(const void* g, void* l) {
  __builtin_amdgcn_global_load_lds(
      (const __attribute__((address_space(1))) unsigned int*)g,
      (__attribute__((address_space(3))) unsigned int*)l, 16, 0, 0);
}
__device__ __forceinline__ float sigmoidf_(float v) { return 1.f / (1.f + __expf(-v)); }

// ---------------- weight prep: all six 128x128 matrices -> MFMA B-fragment order --------
// Wp[m*16384 + (cf*4+kf)*512 + lane*8 + e] = bf16( w_m[kf*32 + (lane>>4)*8 + e][cf*16 + (lane&15)] )
// m: 0=wa 1=wga 2=wb 3=wgb 4=wg 5=wo. Wave fragment load = uniform base + lane*16B.
__global__ void kW(const float* __restrict__ wa, const float* __restrict__ wga,
                   const float* __restrict__ wb, const float* __restrict__ wgb,
                   const float* __restrict__ wg, const float* __restrict__ wo,
                   u16* __restrict__ Wp) {
  int b = blockIdx.x, t = threadIdx.x;
  int m = b >> 5, cf = (b >> 2) & 7, kf = b & 3;
  const float* m6[6] = {wa, wga, wb, wgb, wg, wo};
  const float* src = m6[m];
  int lane = t >> 1, e0 = (t & 1) * 4;
  u16* dst = Wp + m * 16384 + (cf * 4 + kf) * 512 + lane * 8 + e0;
  int col = cf * 16 + (lane & 15);
  int row0 = kf * 32 + (lane >> 4) * 8 + e0;
#pragma unroll
  for (int e = 0; e < 4; ++e) dst[e] = f2bf(src[(row0 + e) * 128 + col]);
}

// ---------------- kernel A: LN + 4 projections + gating -> n1_t, n2_t ([h][i][k] bf16) ----
__global__ void __launch_bounds__(256)
    __attribute__((amdgpu_waves_per_eu(4, 4)))
    kA(const float* __restrict__ x, const float* __restrict__ zn_s,
       const float* __restrict__ zn_b, const float* __restrict__ b_a,
       const float* __restrict__ b_ga, const float* __restrict__ b_b,
       const float* __restrict__ b_gb, const u16* __restrict__ Wp,
       u16* __restrict__ n1t, u16* __restrict__ n2t) {
  __shared__ __align__(16) u16 z[128 * 136];
  int tid = threadIdx.x;
  int pos0 = blockIdx.x * 128;
  int lane = tid & 63, w = tid >> 6;

  {  // single-pass LN: 2 threads per row, x held in registers
    int r = tid >> 1, hf = tid & 1;
    const float* px = x + (size_t)pos0 * 128 + r * 128 + hf * 64;
    float4 xv[16];
    float s = 0.f, s2 = 0.f;
#pragma unroll
    for (int q = 0; q < 16; ++q) {
      xv[q] = *(const float4*)(px + q * 4);
      s += xv[q].x + xv[q].y + xv[q].z + xv[q].w;
      s2 += xv[q].x * xv[q].x + xv[q].y * xv[q].y + xv[q].z * xv[q].z + xv[q].w * xv[q].w;
    }
    s += __shfl_xor(s, 1);
    s2 += __shfl_xor(s2, 1);
    float mu = s * (1.f / 128.f);
    float rs = rsqrtf(s2 * (1.f / 128.f) - mu * mu + 1e-5f);
#pragma unroll
    for (int q = 0; q < 16; ++q) {
      int c0 = hf * 64 + q * 4;
      u16x4 o;
      o[0] = f2bf((xv[q].x - mu) * rs * zn_s[c0 + 0] + zn_b[c0 + 0]);
      o[1] = f2bf((xv[q].y - mu) * rs * zn_s[c0 + 1] + zn_b[c0 + 1]);
      o[2] = f2bf((xv[q].z - mu) * rs * zn_s[c0 + 2] + zn_b[c0 + 2]);
      o[3] = f2bf((xv[q].w - mu) * rs * zn_s[c0 + 3] + zn_b[c0 + 3]);
      *(u16x4*)&z[r * 136 + c0] = o;
    }
  }
  __syncthreads();

  bf16x8 af[2][4];
#pragma unroll
  for (int rf = 0; rf < 2; ++rf)
#pragma unroll
    for (int kf = 0; kf < 4; ++kf)
      af[rf][kf] = *(const bf16x8*)&z[(w * 32 + rf * 16 + (lane & 15)) * 136 + kf * 32 + (lane >> 4) * 8];

  int colL = lane & 15;

#pragma unroll 1
  for (int g = 0; g < 2; ++g) {
    const float* bxp = g ? b_b : b_a;
    const float* bgp = g ? b_gb : b_ga;
    u16* dst = g ? n2t : n1t;
    const u16* WxP = Wp + (g * 2) * 16384 + lane * 8;
    const u16* WgP = Wp + (g * 2 + 1) * 16384 + lane * 8;

    bf16x8 wxf[2][4], wgf[2][4];  // 2-deep double buffer
#pragma unroll
    for (int kf = 0; kf < 4; ++kf) {
      wxf[0][kf] = *(const bf16x8*)&WxP[kf * 512];
      wgf[0][kf] = *(const bf16x8*)&WgP[kf * 512];
    }

#pragma unroll
    for (int cf = 0; cf < 8; ++cf) {
      int cb = cf & 1, nb = cb ^ 1;
      if (cf < 7) {
#pragma unroll
        for (int kf = 0; kf < 4; ++kf) {
          wxf[nb][kf] = *(const bf16x8*)&WxP[((cf + 1) * 4 + kf) * 512];
          wgf[nb][kf] = *(const bf16x8*)&WgP[((cf + 1) * 4 + kf) * 512];
        }
      }
      f32x4 ax0 = {0.f, 0.f, 0.f, 0.f}, ax1 = ax0, ag0 = ax0, ag1 = ax0;
#pragma unroll
      for (int kf = 0; kf < 4; ++kf) {
        ax0 = mfma16(af[0][kf], wxf[cb][kf], ax0);
        ax1 = mfma16(af[1][kf], wxf[cb][kf], ax1);
        ag0 = mfma16(af[0][kf], wgf[cb][kf], ag0);
        ag1 = mfma16(af[1][kf], wgf[cb][kf], ag1);
      }
      int h = cf * 16 + colL;
      float bx_ = bxp[h], bg_ = bgp[h];
      size_t hb = (size_t)h * NP + pos0 + w * 32 + (lane >> 4) * 4;
      u16x4 o0, o1;
#pragma unroll
      for (int r = 0; r < 4; ++r) {
        o0[r] = f2bf((ax0[r] + bx_) * sigmoidf_(ag0[r] + bg_));
        o1[r] = f2bf((ax1[r] + bx_) * sigmoidf_(ag1[r] + bg_));
      }
      *(u16x4*)&dst[hb] = o0;
      *(u16x4*)&dst[hb + 16] = o1;
    }
  }
}

// ---------------- kernel B: per-h NT GEMM  P[h][i][j] = sum_k n1[h][i][k]*n2[h][j][k] -----
__global__ __launch_bounds__(256) void kB(const u16* __restrict__ n1t,
                                          const u16* __restrict__ n2t,
                                          u16* __restrict__ P) {
  __shared__ __align__(16) u16 At[2][128 * 64];
  __shared__ __align__(16) u16 Bt[2][128 * 64];
  int bid = blockIdx.x;
  int h = bid >> 4, t = bid & 15;
  int i0 = (t >> 2) * 128, j0 = (t & 3) * 128;
  const u16* Ab = n1t + (size_t)h * NP + (size_t)i0 * 512;
  const u16* Bb = n2t + (size_t)h * NP + (size_t)j0 * 512;
  int tid = threadIdx.x, lane = tid & 63, w = tid >> 6;

  f32x4 acc[4][4];
#pragma unroll
  for (int a_ = 0; a_ < 4; ++a_)
#pragma unroll
    for (int b_ = 0; b_ < 4; ++b_) acc[a_][b_] = f32x4{0.f, 0.f, 0.f, 0.f};

  auto STAGE = [&](int buf, int kt) {
#pragma unroll
    for (int q = 0; q < 4; ++q) {
      int c = q * 256 + tid;
      int row = c >> 3, ch = c & 7;
      int chG = ch ^ (row & 7);
      gload16(Ab + (size_t)row * 512 + kt * 64 + chG * 8, &At[buf][c * 8]);
    }
#pragma unroll
    for (int q = 0; q < 4; ++q) {
      int c = q * 256 + tid;
      int row = c >> 3, ch = c & 7;
      int chG = ch ^ (row & 7);
      gload16(Bb + (size_t)row * 512 + kt * 64 + chG * 8, &Bt[buf][c * 8]);
    }
  };

  STAGE(0, 0);
  int cur = 0;
  int r0 = (w >> 1) * 64, c0 = (w & 1) * 64;
#pragma unroll 1
  for (int kt = 0; kt < 8; ++kt) {
    if (kt < 7) {
      STAGE(cur ^ 1, kt + 1);
      __builtin_amdgcn_sched_barrier(0);
      asm volatile("s_waitcnt vmcnt(8)" ::: "memory");
    } else {
      asm volatile("s_waitcnt vmcnt(0)" ::: "memory");
    }
    __builtin_amdgcn_sched_barrier(0);
    __builtin_amdgcn_s_barrier();
    __builtin_amdgcn_sched_barrier(0);
#pragma unroll
    for (int kf = 0; kf < 2; ++kf) {
      bf16x8 a[4], b[4];
#pragma unroll
      for (int rf = 0; rf < 4; ++rf) {
        int row = r0 + rf * 16 + (lane & 15);
        a[rf] = *(const bf16x8*)&At[cur][row * 64 + (((kf * 4 + (lane >> 4)) ^ (row & 7)) * 8)];
      }
#pragma unroll
      for (int cf = 0; cf < 4; ++cf) {
        int row = c0 + cf * 16 + (lane & 15);
        b[cf] = *(const bf16x8*)&Bt[cur][row * 64 + (((kf * 4 + (lane >> 4)) ^ (row & 7)) * 8)];
      }
#pragma unroll
      for (int rf = 0; rf < 4; ++rf)
#pragma unroll
        for (int cf = 0; cf < 4; ++cf) acc[rf][cf] = mfma16(a[rf], b[cf], acc[rf][cf]);
    }
    __builtin_amdgcn_sched_barrier(0);
    __builtin_amdgcn_s_barrier();
    __builtin_amdgcn_sched_barrier(0);
    cur ^= 1;
  }

  size_t Pb = (size_t)h * NP;
#pragma unroll
  for (int rf = 0; rf < 4; ++rf)
#pragma unroll
    for (int cf = 0; cf < 4; ++cf) {
      int ii = i0 + (w >> 1) * 64 + rf * 16 + (lane >> 4) * 4;
      int jj = j0 + (w & 1) * 64 + cf * 16 + (lane & 15);
#pragma unroll
      for (int r = 0; r < 4; ++r) P[Pb + (size_t)(ii + r) * 512 + jj] = f2bf(acc[rf][cf][r]);
    }
}

// ---------------- kernel C: LN over h, @w_o + b_o, * sigmoid(z@w_g + b_g) -----------------
// ONE 34.8 KB LDS buffer time-shared: (1) LN(x) -> az frags; (2) transposed P + LN-h -> ap
// frags; (3) MFMA with Wo/Wg fragments straight from packed global. 4 blocks/CU.
__global__ void __launch_bounds__(256)
    __attribute__((amdgpu_waves_per_eu(4, 4)))
    kC(const float* __restrict__ x, const u16* __restrict__ P,
       const float* __restrict__ zn_s, const float* __restrict__ zn_b,
       const float* __restrict__ ln_s, const float* __restrict__ ln_b,
       const u16* __restrict__ Wp, const float* __restrict__ b_o,
       const float* __restrict__ b_g, float* __restrict__ out) {
  __shared__ __align__(16) u16 T[128 * 136];
  int tid = threadIdx.x, lane = tid & 63, w = tid >> 6;
  int i = blockIdx.x >> 2, jb = blockIdx.x & 3;
  size_t pos0 = (size_t)i * 512 + jb * 128;

  // ---- phase 1: z = LN(x) rows -> T; grab az fragments ----
  {
    int r = tid >> 1, hf = tid & 1;
    const float* px = x + pos0 * 128 + r * 128 + hf * 64;
    float4 xv[16];
    float s = 0.f, s2 = 0.f;
#pragma unroll
    for (int q = 0; q < 16; ++q) {
      xv[q] = *(const float4*)(px + q * 4);
      s += xv[q].x + xv[q].y + xv[q].z + xv[q].w;
      s2 += xv[q].x * xv[q].x + xv[q].y * xv[q].y + xv[q].z * xv[q].z + xv[q].w * xv[q].w;
    }
    s += __shfl_xor(s, 1);
    s2 += __shfl_xor(s2, 1);
    float mu = s * (1.f / 128.f);
    float rs = rsqrtf(s2 * (1.f / 128.f) - mu * mu + 1e-5f);
#pragma unroll
    for (int q = 0; q < 16; ++q) {
      int c0 = hf * 64 + q * 4;
      u16x4 o;
      o[0] = f2bf((xv[q].x - mu) * rs * zn_s[c0 + 0] + zn_b[c0 + 0]);
      o[1] = f2bf((xv[q].y - mu) * rs * zn_s[c0 + 1] + zn_b[c0 + 1]);
      o[2] = f2bf((xv[q].z - mu) * rs * zn_s[c0 + 2] + zn_b[c0 + 2]);
      o[3] = f2bf((xv[q].w - mu) * rs * zn_s[c0 + 3] + zn_b[c0 + 3]);
      *(u16x4*)&T[r * 136 + c0] = o;
    }
  }
  __syncthreads();
  bf16x8 az[2][4];
#pragma unroll
  for (int rf = 0; rf < 2; ++rf)
#pragma unroll
    for (int kf = 0; kf < 4; ++kf)
      az[rf][kf] = *(const bf16x8*)&T[(w * 32 + rf * 16 + (lane & 15)) * 136 + kf * 32 + (lane >> 4) * 8];
  __syncthreads();  // all az reads done before T is overwritten

  // ---- phase 2: transpose P[h][i][j-tile] -> T[j][h] via 8x8 register subtiles ----
  {
    int sh = tid & 15, sj = tid >> 4;  // h-subtile, j-subtile (16x16 grid of 8x8)
    const u16* src = P + (size_t)(sh * 8) * NP + pos0 + sj * 8;
    u16x8 vv[8];
#pragma unroll
    for (int e = 0; e < 8; ++e) vv[e] = *(const u16x8*)(src + (size_t)e * NP);
#pragma unroll
    for (int f = 0; f < 8; ++f) {
      u16x8 ww;
#pragma unroll
      for (int e = 0; e < 8; ++e) ww[e] = vv[e][f];
      *(u16x8*)&T[(sj * 8 + f) * 136 + sh * 8] = ww;
    }
  }
  __syncthreads();

  // ---- LN over h, in place (2 threads per row) ----
  {
    int r = tid >> 1, hf = tid & 1;
    u16x8 vq[8];
    float s = 0.f, s2 = 0.f;
#pragma unroll
    for (int q = 0; q < 8; ++q) {
      vq[q] = *(const u16x8*)&T[r * 136 + hf * 64 + q * 8];
#pragma unroll
      for (int e = 0; e < 8; ++e) {
        float f = bf2f(vq[q][e]);
        s += f;
        s2 += f * f;
      }
    }
    s += __shfl_xor(s, 1);
    s2 += __shfl_xor(s2, 1);
    float mu = s * (1.f / 128.f);
    float rs = rsqrtf(s2 * (1.f / 128.f) - mu * mu + 1e-5f);
#pragma unroll
    for (int q = 0; q < 8; ++q) {
      u16x8 o;
#pragma unroll
      for (int e = 0; e < 8; ++e) {
        int hh = hf * 64 + q * 8 + e;
        o[e] = f2bf((bf2f(vq[q][e]) - mu) * rs * ln_s[hh] + ln_b[hh]);
      }
      *(u16x8*)&T[r * 136 + hf * 64 + q * 8] = o;
    }
  }
  __syncthreads();

  bf16x8 ap[2][4];
#pragma unroll
  for (int rf = 0; rf < 2; ++rf)
#pragma unroll
    for (int kf = 0; kf < 4; ++kf)
      ap[rf][kf] = *(const bf16x8*)&T[(w * 32 + rf * 16 + (lane & 15)) * 136 + kf * 32 + (lane >> 4) * 8];

  // ---- phase 3: MFMA with packed global weight fragments ----
  const u16* WgP = Wp + 4 * 16384 + lane * 8;
  const u16* WoP = Wp + 5 * 16384 + lane * 8;

#pragma unroll 1
  for (int sub = 0; sub < 4; ++sub) {
    f32x4 au[2][2], agg[2][2];
#pragma unroll
    for (int rf = 0; rf < 2; ++rf)
#pragma unroll
      for (int cf = 0; cf < 2; ++cf) {
        au[rf][cf] = f32x4{0.f, 0.f, 0.f, 0.f};
        agg[rf][cf] = f32x4{0.f, 0.f, 0.f, 0.f};
      }
#pragma unroll
    for (int cf = 0; cf < 2; ++cf) {
      int cg = sub * 2 + cf;
#pragma unroll
      for (int kf = 0; kf < 4; ++kf) {
        bf16x8 bo_f = *(const bf16x8*)&WoP[(cg * 4 + kf) * 512];
        bf16x8 bg_f = *(const bf16x8*)&WgP[(cg * 4 + kf) * 512];
#pragma unroll
        for (int rf = 0; rf < 2; ++rf) {
          au[rf][cf] = mfma16(ap[rf][kf], bo_f, au[rf][cf]);
          agg[rf][cf] = mfma16(az[rf][kf], bg_f, agg[rf][cf]);
        }
      }
    }
#pragma unroll
    for (int rf = 0; rf < 2; ++rf)
#pragma unroll
      for (int cf = 0; cf < 2; ++cf) {
        int d = sub * 32 + cf * 16 + (lane & 15);
        float bo_ = b_o[d], bg_ = b_g[d];
        int jl = w * 32 + rf * 16 + (lane >> 4) * 4;
#pragma unroll
        for (int r = 0; r < 4; ++r) {
          float uv = au[rf][cf][r] + bo_;
          out[(pos0 + jl + r) * 128 + d] = uv * sigmoidf_(agg[rf][cf][r] + bg_);
        }
      }
  }
}

extern "C" void kernel_launch(void* const* d_in, const int* in_sizes, int n_in,
                              void* d_out, int out_size, void* d_ws, size_t ws_size,
                              hipStream_t stream) {
  const float* x = (const float*)d_in[0];
  const float* zn_s = (const float*)d_in[1];
  const float* zn_b = (const float*)d_in[2];
  const float* ln_s = (const float*)d_in[3];
  const float* ln_b = (const float*)d_in[4];
  const float* w_a = (const float*)d_in[5];
  const float* b_a = (const float*)d_in[6];
  const float* w_ga = (const float*)d_in[7];
  const float* b_ga = (const float*)d_in[8];
  const float* w_b = (const float*)d_in[9];
  const float* b_b = (const float*)d_in[10];
  const float* w_gb = (const float*)d_in[11];
  const float* b_gb = (const float*)d_in[12];
  const float* w_o = (const float*)d_in[13];
  const float* b_o = (const float*)d_in[14];
  const float* w_g = (const float*)d_in[15];
  const float* b_g = (const float*)d_in[16];

  char* ws = (char*)d_ws;
  u16* n1t = (u16*)ws;                         // [128][512][512] bf16, 64 MB
  u16* n2t = (u16*)(ws + 67108864);            // 64 MB
  u16* P = (u16*)(ws + 134217728);             // [128][512][512] bf16, 64 MB
  u16* Wp = (u16*)(ws + 201326592);            // packed 6x[128x128] bf16, 192 KB

  kW<<<192, 128, 0, stream>>>(w_a, w_ga, w_b, w_gb, w_g, w_o, Wp);
  kA<<<2048, 256, 0, stream>>>(x, zn_s, zn_b, b_a, b_ga, b_b, b_gb, Wp, n1t, n2t);
  kB<<<2048, 256, 0, stream>>>(n1t, n2t, P);
  kC<<<2048, 256, 0, stream>>>(x, P, zn_s, zn_b, ln_s, ln_b, Wp, b_o, b_g, (float*)d_out);
}

// Round 8
// 283.715 us; speedup vs baseline: 1.4496x; 1.0814x over previous
//
#include <hip/hip_runtime.h>

#define NSEQ 512
#define DD 128
#define NP (NSEQ * NSEQ)

typedef unsigned short u16;
typedef __attribute__((ext_vector_type(8))) unsigned short u16x8;
typedef __attribute__((ext_vector_type(4))) unsigned short u16x4;
typedef __attribute__((ext_vector_type(8))) short bf16x8;
typedef __attribute__((ext_vector_type(4))) float f32x4;

__device__ __forceinline__ u16 f2bf(float f) {
  unsigned int x = __float_as_uint(f);
  return (u16)((x + 0x7fffu + ((x >> 16) & 1u)) >> 16);  // RNE
}
__device__ __forceinline__ float bf2f(u16 u) {
  return __uint_as_float(((unsigned int)u) << 16);
}
__device__ __forceinline__ f32x4 mfma16(bf16x8 a, bf16x8 b, f32x4 c) {
  return __builtin_amdgcn_mfma_f32_16x16x32_bf16(a, b, c, 0, 0, 0);
}
__device__ __forceinline__ void gload16(const void* g, void* l) {
  __builtin_amdgcn_global_load_lds(
      (const __attribute__((address_space(1))) unsigned int*)g,
      (__attribute__((address_space(3))) unsigned int*)l, 16, 0, 0);
}
__device__ __forceinline__ float sigmoidf_(float v) { return 1.f / (1.f + __expf(-v)); }

// ---------------- weight prep: all six 128x128 matrices -> MFMA fragment order ----------
// Wp[m*16384 + (cf*4+kf)*512 + lane*8 + e] = bf16( w_m[kf*32 + (lane>>4)*8 + e][cf*16 + (lane&15)] )
// Works as B-fragment (col = lane&15) AND as A-fragment (row = lane&15) — layouts coincide.
__global__ void kW(const float* __restrict__ wa, const float* __restrict__ wga,
                   const float* __restrict__ wb, const float* __restrict__ wgb,
                   const float* __restrict__ wg, const float* __restrict__ wo,
                   u16* __restrict__ Wp) {
  int b = blockIdx.x, t = threadIdx.x;
  int m = b >> 5, cf = (b >> 2) & 7, kf = b & 3;
  const float* m6[6] = {wa, wga, wb, wgb, wg, wo};
  const float* src = m6[m];
  int lane = t >> 1, e0 = (t & 1) * 4;
  u16* dst = Wp + m * 16384 + (cf * 4 + kf) * 512 + lane * 8 + e0;
  int col = cf * 16 + (lane & 15);
  int row0 = kf * 32 + (lane >> 4) * 8 + e0;
#pragma unroll
  for (int e = 0; e < 4; ++e) dst[e] = f2bf(src[(row0 + e) * 128 + col]);
}

// ---------------- kernel A: LN + 4 projections + gating -> n1_t, n2_t ([h][i] bf16) ------
// Operand-swapped GEMM: D = W (A-op) x z^T (B-op) -> D[h][pos], stores already transposed.
// Each wave owns h-strip [w*32, w*32+32): its 16 weight fragments + biases are hoisted out
// of the pos loop -> inner loop is ds_read + MFMA + epilogue only.
__global__ void __launch_bounds__(256)
    __attribute__((amdgpu_waves_per_eu(4, 4)))
    kA(const float* __restrict__ x, const float* __restrict__ zn_s,
       const float* __restrict__ zn_b, const float* __restrict__ b_a,
       const float* __restrict__ b_ga, const float* __restrict__ b_b,
       const float* __restrict__ b_gb, const u16* __restrict__ Wp,
       u16* __restrict__ n1t, u16* __restrict__ n2t) {
  __shared__ __align__(16) u16 z[128 * 136];
  int tid = threadIdx.x;
  int pos0 = blockIdx.x * 128;
  int lane = tid & 63, w = tid >> 6;

  {  // single-pass LN: 2 threads per row, x held in registers
    int r = tid >> 1, hf = tid & 1;
    const float* px = x + (size_t)pos0 * 128 + r * 128 + hf * 64;
    float4 xv[16];
    float s = 0.f, s2 = 0.f;
#pragma unroll
    for (int q = 0; q < 16; ++q) {
      xv[q] = *(const float4*)(px + q * 4);
      s += xv[q].x + xv[q].y + xv[q].z + xv[q].w;
      s2 += xv[q].x * xv[q].x + xv[q].y * xv[q].y + xv[q].z * xv[q].z + xv[q].w * xv[q].w;
    }
    s += __shfl_xor(s, 1);
    s2 += __shfl_xor(s2, 1);
    float mu = s * (1.f / 128.f);
    float rs = rsqrtf(s2 * (1.f / 128.f) - mu * mu + 1e-5f);
#pragma unroll
    for (int q = 0; q < 16; ++q) {
      int c0 = hf * 64 + q * 4;
      u16x4 o;
      o[0] = f2bf((xv[q].x - mu) * rs * zn_s[c0 + 0] + zn_b[c0 + 0]);
      o[1] = f2bf((xv[q].y - mu) * rs * zn_s[c0 + 1] + zn_b[c0 + 1]);
      o[2] = f2bf((xv[q].z - mu) * rs * zn_s[c0 + 2] + zn_b[c0 + 2]);
      o[3] = f2bf((xv[q].w - mu) * rs * zn_s[c0 + 3] + zn_b[c0 + 3]);
      *(u16x4*)&z[r * 136 + c0] = o;
    }
  }
  __syncthreads();  // every wave reads all 128 z rows below

  int quad = lane >> 4, colL = lane & 15;

#pragma unroll 1
  for (int g = 0; g < 2; ++g) {
    const float* bxp = g ? b_b : b_a;
    const float* bgp = g ? b_gb : b_ga;
    u16* dst = g ? n2t : n1t;
    const u16* WxP = Wp + (g * 2) * 16384 + lane * 8;
    const u16* WgP = Wp + (g * 2 + 1) * 16384 + lane * 8;

    // hoisted: this wave's weight fragments (cf = 2w, 2w+1) and biases
    bf16x8 wxf[2][4], wgf[2][4];
    float bx[2][4], bg[2][4];
#pragma unroll
    for (int c2 = 0; c2 < 2; ++c2) {
      int cf = w * 2 + c2;
#pragma unroll
      for (int kf = 0; kf < 4; ++kf) {
        wxf[c2][kf] = *(const bf16x8*)&WxP[(cf * 4 + kf) * 512];
        wgf[c2][kf] = *(const bf16x8*)&WgP[(cf * 4 + kf) * 512];
      }
#pragma unroll
      for (int r = 0; r < 4; ++r) {
        int h = cf * 16 + quad * 4 + r;
        bx[c2][r] = bxp[h];
        bg[c2][r] = bgp[h];
      }
    }

#pragma unroll 1
    for (int n = 0; n < 8; ++n) {
      bf16x8 zb[4];
#pragma unroll
      for (int kf = 0; kf < 4; ++kf)
        zb[kf] = *(const bf16x8*)&z[(n * 16 + colL) * 136 + kf * 32 + quad * 8];
      f32x4 au0 = {0.f, 0.f, 0.f, 0.f}, au1 = au0, ag0 = au0, ag1 = au0;
#pragma unroll
      for (int kf = 0; kf < 4; ++kf) {
        au0 = mfma16(wxf[0][kf], zb[kf], au0);
        au1 = mfma16(wxf[1][kf], zb[kf], au1);
        ag0 = mfma16(wgf[0][kf], zb[kf], ag0);
        ag1 = mfma16(wgf[1][kf], zb[kf], ag1);
      }
      int pos = pos0 + n * 16 + colL;
#pragma unroll
      for (int r = 0; r < 4; ++r) {
        int h0 = (w * 2) * 16 + quad * 4 + r;
        int h1 = (w * 2 + 1) * 16 + quad * 4 + r;
        float v0 = (au0[r] + bx[0][r]) * sigmoidf_(ag0[r] + bg[0][r]);
        float v1 = (au1[r] + bx[1][r]) * sigmoidf_(ag1[r] + bg[1][r]);
        dst[(size_t)h0 * NP + pos] = f2bf(v0);
        dst[(size_t)h1 * NP + pos] = f2bf(v1);
      }
    }
  }
}

// ---------------- kernel B: per-h NT GEMM  P[h][i][j] = sum_k n1[h][i][k]*n2[h][j][k] -----
__global__ __launch_bounds__(256) void kB(const u16* __restrict__ n1t,
                                          const u16* __restrict__ n2t,
                                          u16* __restrict__ P) {
  __shared__ __align__(16) u16 At[2][128 * 64];
  __shared__ __align__(16) u16 Bt[2][128 * 64];
  int bid = blockIdx.x;
  int h = bid >> 4, t = bid & 15;
  int i0 = (t >> 2) * 128, j0 = (t & 3) * 128;
  const u16* Ab = n1t + (size_t)h * NP + (size_t)i0 * 512;
  const u16* Bb = n2t + (size_t)h * NP + (size_t)j0 * 512;
  int tid = threadIdx.x, lane = tid & 63, w = tid >> 6;

  f32x4 acc[4][4];
#pragma unroll
  for (int a_ = 0; a_ < 4; ++a_)
#pragma unroll
    for (int b_ = 0; b_ < 4; ++b_) acc[a_][b_] = f32x4{0.f, 0.f, 0.f, 0.f};

  auto STAGE = [&](int buf, int kt) {
#pragma unroll
    for (int q = 0; q < 4; ++q) {
      int c = q * 256 + tid;
      int row = c >> 3, ch = c & 7;
      int chG = ch ^ (row & 7);
      gload16(Ab + (size_t)row * 512 + kt * 64 + chG * 8, &At[buf][c * 8]);
    }
#pragma unroll
    for (int q = 0; q < 4; ++q) {
      int c = q * 256 + tid;
      int row = c >> 3, ch = c & 7;
      int chG = ch ^ (row & 7);
      gload16(Bb + (size_t)row * 512 + kt * 64 + chG * 8, &Bt[buf][c * 8]);
    }
  };

  STAGE(0, 0);
  int cur = 0;
  int r0 = (w >> 1) * 64, c0 = (w & 1) * 64;
#pragma unroll 1
  for (int kt = 0; kt < 8; ++kt) {
    if (kt < 7) {
      STAGE(cur ^ 1, kt + 1);
      __builtin_amdgcn_sched_barrier(0);
      asm volatile("s_waitcnt vmcnt(8)" ::: "memory");
    } else {
      asm volatile("s_waitcnt vmcnt(0)" ::: "memory");
    }
    __builtin_amdgcn_sched_barrier(0);
    __builtin_amdgcn_s_barrier();
    __builtin_amdgcn_sched_barrier(0);
#pragma unroll
    for (int kf = 0; kf < 2; ++kf) {
      bf16x8 a[4], b[4];
#pragma unroll
      for (int rf = 0; rf < 4; ++rf) {
        int row = r0 + rf * 16 + (lane & 15);
        a[rf] = *(const bf16x8*)&At[cur][row * 64 + (((kf * 4 + (lane >> 4)) ^ (row & 7)) * 8)];
      }
#pragma unroll
      for (int cf = 0; cf < 4; ++cf) {
        int row = c0 + cf * 16 + (lane & 15);
        b[cf] = *(const bf16x8*)&Bt[cur][row * 64 + (((kf * 4 + (lane >> 4)) ^ (row & 7)) * 8)];
      }
#pragma unroll
      for (int rf = 0; rf < 4; ++rf)
#pragma unroll
        for (int cf = 0; cf < 4; ++cf) acc[rf][cf] = mfma16(a[rf], b[cf], acc[rf][cf]);
    }
    __builtin_amdgcn_sched_barrier(0);
    __builtin_amdgcn_s_barrier();
    __builtin_amdgcn_sched_barrier(0);
    cur ^= 1;
  }

  size_t Pb = (size_t)h * NP;
#pragma unroll
  for (int rf = 0; rf < 4; ++rf)
#pragma unroll
    for (int cf = 0; cf < 4; ++cf) {
      int ii = i0 + (w >> 1) * 64 + rf * 16 + (lane >> 4) * 4;
      int jj = j0 + (w & 1) * 64 + cf * 16 + (lane & 15);
#pragma unroll
      for (int r = 0; r < 4; ++r) P[Pb + (size_t)(ii + r) * 512 + jj] = f2bf(acc[rf][cf][r]);
    }
}

// ---------------- kernel C: LN over h, @w_o + b_o, * sigmoid(z@w_g + b_g) -----------------
__global__ void __launch_bounds__(256)
    __attribute__((amdgpu_waves_per_eu(4, 4)))
    kC(const float* __restrict__ x, const u16* __restrict__ P,
       const float* __restrict__ zn_s, const float* __restrict__ zn_b,
       const float* __restrict__ ln_s, const float* __restrict__ ln_b,
       const u16* __restrict__ Wp, const float* __restrict__ b_o,
       const float* __restrict__ b_g, float* __restrict__ out) {
  __shared__ __align__(16) u16 T[128 * 136];
  int tid = threadIdx.x, lane = tid & 63, w = tid >> 6;
  int i = blockIdx.x >> 2, jb = blockIdx.x & 3;
  size_t pos0 = (size_t)i * 512 + jb * 128;

  // ---- phase 1: z = LN(x) rows -> T; grab az fragments ----
  {
    int r = tid >> 1, hf = tid & 1;
    const float* px = x + pos0 * 128 + r * 128 + hf * 64;
    float4 xv[16];
    float s = 0.f, s2 = 0.f;
#pragma unroll
    for (int q = 0; q < 16; ++q) {
      xv[q] = *(const float4*)(px + q * 4);
      s += xv[q].x + xv[q].y + xv[q].z + xv[q].w;
      s2 += xv[q].x * xv[q].x + xv[q].y * xv[q].y + xv[q].z * xv[q].z + xv[q].w * xv[q].w;
    }
    s += __shfl_xor(s, 1);
    s2 += __shfl_xor(s2, 1);
    float mu = s * (1.f / 128.f);
    float rs = rsqrtf(s2 * (1.f / 128.f) - mu * mu + 1e-5f);
#pragma unroll
    for (int q = 0; q < 16; ++q) {
      int c0 = hf * 64 + q * 4;
      u16x4 o;
      o[0] = f2bf((xv[q].x - mu) * rs * zn_s[c0 + 0] + zn_b[c0 + 0]);
      o[1] = f2bf((xv[q].y - mu) * rs * zn_s[c0 + 1] + zn_b[c0 + 1]);
      o[2] = f2bf((xv[q].z - mu) * rs * zn_s[c0 + 2] + zn_b[c0 + 2]);
      o[3] = f2bf((xv[q].w - mu) * rs * zn_s[c0 + 3] + zn_b[c0 + 3]);
      *(u16x4*)&T[r * 136 + c0] = o;
    }
  }
  __syncthreads();
  bf16x8 az[2][4];
#pragma unroll
  for (int rf = 0; rf < 2; ++rf)
#pragma unroll
    for (int kf = 0; kf < 4; ++kf)
      az[rf][kf] = *(const bf16x8*)&T[(w * 32 + rf * 16 + (lane & 15)) * 136 + kf * 32 + (lane >> 4) * 8];
  __syncthreads();  // all az reads done before T is overwritten

  // ---- phase 2: transpose P[h][i][j-tile] -> T[j][h] via 8x8 register subtiles ----
  {
    int sh = tid & 15, sj = tid >> 4;
    const u16* src = P + (size_t)(sh * 8) * NP + pos0 + sj * 8;
    u16x8 vv[8];
#pragma unroll
    for (int e = 0; e < 8; ++e) vv[e] = *(const u16x8*)(src + (size_t)e * NP);
#pragma unroll
    for (int f = 0; f < 8; ++f) {
      u16x8 ww;
#pragma unroll
      for (int e = 0; e < 8; ++e) ww[e] = vv[e][f];
      *(u16x8*)&T[(sj * 8 + f) * 136 + sh * 8] = ww;
    }
  }
  __syncthreads();

  // ---- LN over h, in place (2 threads per row) ----
  {
    int r = tid >> 1, hf = tid & 1;
    u16x8 vq[8];
    float s = 0.f, s2 = 0.f;
#pragma unroll
    for (int q = 0; q < 8; ++q) {
      vq[q] = *(const u16x8*)&T[r * 136 + hf * 64 + q * 8];
#pragma unroll
      for (int e = 0; e < 8; ++e) {
        float f = bf2f(vq[q][e]);
        s += f;
        s2 += f * f;
      }
    }
    s += __shfl_xor(s, 1);
    s2 += __shfl_xor(s2, 1);
    float mu = s * (1.f / 128.f);
    float rs = rsqrtf(s2 * (1.f / 128.f) - mu * mu + 1e-5f);
#pragma unroll
    for (int q = 0; q < 8; ++q) {
      u16x8 o;
#pragma unroll
      for (int e = 0; e < 8; ++e) {
        int hh = hf * 64 + q * 8 + e;
        o[e] = f2bf((bf2f(vq[q][e]) - mu) * rs * ln_s[hh] + ln_b[hh]);
      }
      *(u16x8*)&T[r * 136 + hf * 64 + q * 8] = o;
    }
  }
  __syncthreads();

  bf16x8 ap[2][4];
#pragma unroll
  for (int rf = 0; rf < 2; ++rf)
#pragma unroll
    for (int kf = 0; kf < 4; ++kf)
      ap[rf][kf] = *(const bf16x8*)&T[(w * 32 + rf * 16 + (lane & 15)) * 136 + kf * 32 + (lane >> 4) * 8];

  // ---- phase 3: MFMA with packed global weight fragments ----
  const u16* WgP = Wp + 4 * 16384 + lane * 8;
  const u16* WoP = Wp + 5 * 16384 + lane * 8;

#pragma unroll 1
  for (int sub = 0; sub < 4; ++sub) {
    f32x4 au[2][2], agg[2][2];
#pragma unroll
    for (int rf = 0; rf < 2; ++rf)
#pragma unroll
      for (int cf = 0; cf < 2; ++cf) {
        au[rf][cf] = f32x4{0.f, 0.f, 0.f, 0.f};
        agg[rf][cf] = f32x4{0.f, 0.f, 0.f, 0.f};
      }
#pragma unroll
    for (int cf = 0; cf < 2; ++cf) {
      int cg = sub * 2 + cf;
#pragma unroll
      for (int kf = 0; kf < 4; ++kf) {
        bf16x8 bo_f = *(const bf16x8*)&WoP[(cg * 4 + kf) * 512];
        bf16x8 bg_f = *(const bf16x8*)&WgP[(cg * 4 + kf) * 512];
#pragma unroll
        for (int rf = 0; rf < 2; ++rf) {
          au[rf][cf] = mfma16(ap[rf][kf], bo_f, au[rf][cf]);
          agg[rf][cf] = mfma16(az[rf][kf], bg_f, agg[rf][cf]);
        }
      }
    }
#pragma unroll
    for (int rf = 0; rf < 2; ++rf)
#pragma unroll
      for (int cf = 0; cf < 2; ++cf) {
        int d = sub * 32 + cf * 16 + (lane & 15);
        float bo_ = b_o[d], bg_ = b_g[d];
        int jl = w * 32 + rf * 16 + (lane >> 4) * 4;
#pragma unroll
        for (int r = 0; r < 4; ++r) {
          float uv = au[rf][cf][r] + bo_;
          out[(pos0 + jl + r) * 128 + d] = uv * sigmoidf_(agg[rf][cf][r] + bg_);
        }
      }
  }
}

extern "C" void kernel_launch(void* const* d_in, const int* in_sizes, int n_in,
                              void* d_out, int out_size, void* d_ws, size_t ws_size,
                              hipStream_t stream) {
  const float* x = (const float*)d_in[0];
  const float* zn_s = (const float*)d_in[1];
  const float* zn_b = (const float*)d_in[2];
  const float* ln_s = (const float*)d_in[3];
  const float* ln_b = (const float*)d_in[4];
  const float* w_a = (const float*)d_in[5];
  const float* b_a = (const float*)d_in[6];
  const float* w_ga = (const float*)d_in[7];
  const float* b_ga = (const float*)d_in[8];
  const float* w_b = (const float*)d_in[9];
  const float* b_b = (const float*)d_in[10];
  const float* w_gb = (const float*)d_in[11];
  const float* b_gb = (const float*)d_in[12];
  const float* w_o = (const float*)d_in[13];
  const float* b_o = (const float*)d_in[14];
  const float* w_g = (const float*)d_in[15];
  const float* b_g = (const float*)d_in[16];

  char* ws = (char*)d_ws;
  u16* n1t = (u16*)ws;                         // [128][512][512] bf16, 64 MB
  u16* n2t = (u16*)(ws + 67108864);            // 64 MB
  u16* P = (u16*)(ws + 134217728);             // [128][512][512] bf16, 64 MB
  u16* Wp = (u16*)(ws + 201326592);            // packed 6x[128x128] bf16, 192 KB

  kW<<<192, 128, 0, stream>>>(w_a, w_ga, w_b, w_gb, w_g, w_o, Wp);
  kA<<<2048, 256, 0, stream>>>(x, zn_s, zn_b, b_a, b_ga, b_b, b_gb, Wp, n1t, n2t);
  kB<<<2048, 256, 0, stream>>>(n1t, n2t, P);
  kC<<<2048, 256, 0, stream>>>(x, P, zn_s, zn_b, ln_s, ln_b, Wp, b_o, b_g, (float*)d_out);
}